// Round 1
// baseline (103.129 us; speedup 1.0000x reference)
//
#include <hip/hip_runtime.h>

// Constrained sparsemax: p = clip(z - tau, 0, u) with tau s.t. sum(p) = 1.
// f(tau) = sum_i clip(z_i - tau, 0, u_i) is piecewise linear, non-increasing.
// Safeguarded Newton in float64: candidate tau = (S - 1)/cnt where
// S = sum_active z + sum_saturated u, cnt = #active; bisection fallback on
// bracket [min(z-u), max(z)] (f(lo)=sum u >= 1, f(hi)=0).
// One block of 256 threads per row, K=1024 -> 4 elements/thread in registers.

__global__ __launch_bounds__(256)
void csparsemax_kernel(const float* __restrict__ z, const float* __restrict__ u,
                       float* __restrict__ out, int K, int B) {
  const int row = blockIdx.x;
  const int tid = threadIdx.x;
  const int lane = tid & 63;
  const int wave = tid >> 6;
  const size_t base = (size_t)row * (size_t)K;

  __shared__ double sA[4], sB4[4];

  // --- load 4 elements/thread (float4, 16B/lane coalesced) ---
  const float4 z4 = ((const float4*)(z + base))[tid];
  const float4 u4 = ((const float4*)(u + base))[tid];
  double zd[4], ud[4];
  zd[0] = z4.x; zd[1] = z4.y; zd[2] = z4.z; zd[3] = z4.w;
  ud[0] = u4.x; ud[1] = u4.y; ud[2] = u4.z; ud[3] = u4.w;

  // --- initial bracket: lo = min(z-u) (f=sum u >= 1), hi = max(z) (f=0) ---
  double lo = 1e300, hi = -1e300;
  #pragma unroll
  for (int t = 0; t < 4; ++t) {
    lo = fmin(lo, zd[t] - ud[t]);
    hi = fmax(hi, zd[t]);
  }
  #pragma unroll
  for (int off = 32; off; off >>= 1) {
    lo = fmin(lo, __shfl_down(lo, off));
    hi = fmax(hi, __shfl_down(hi, off));
  }
  if (lane == 0) { sA[wave] = lo; sB4[wave] = hi; }
  __syncthreads();
  lo = fmin(fmin(sA[0], sA[1]), fmin(sA[2], sA[3]));
  hi = fmax(fmax(sB4[0], sB4[1]), fmax(sB4[2], sB4[3]));
  __syncthreads();

  // --- safeguarded Newton / bisection (all decisions block-uniform) ---
  double tau = 0.5 * (lo + hi);
  for (int it = 0; it < 64; ++it) {
    double S = 0.0, C = 0.0;
    #pragma unroll
    for (int t = 0; t < 4; ++t) {
      double x = zd[t] - tau;
      if (x >= ud[t])      { S += ud[t]; }
      else if (x > 0.0)    { S += zd[t]; C += 1.0; }
    }
    #pragma unroll
    for (int off = 32; off; off >>= 1) {
      S += __shfl_down(S, off);
      C += __shfl_down(C, off);
    }
    if (lane == 0) { sA[wave] = S; sB4[wave] = C; }
    __syncthreads();
    S = sA[0] + sA[1] + sA[2] + sA[3];   // identical order on all threads
    C = sB4[0] + sB4[1] + sB4[2] + sB4[3];
    __syncthreads();

    double f = S - C * tau;              // f(tau) = sum_sat u + sum_act z - cnt*tau
    if (f == 1.0 && C > 0.5) break;      // exact root
    if (f > 1.0) lo = tau; else hi = tau;
    double next;
    if (C > 0.5) {
      double cand = (S - 1.0) / C;       // root of current linear segment
      if (cand == tau) break;            // fixed point -> exact root
      next = (cand > lo && cand < hi) ? cand : 0.5 * (lo + hi);
    } else {
      next = 0.5 * (lo + hi);
    }
    if (next == tau) break;              // bracket exhausted at f64 resolution
    tau = next;
  }

  // --- outputs: p [B*K], regions-as-float [B*K], tau [B], val [B] ---
  float* out_p = out;
  float* out_r = out + (size_t)B * (size_t)K;
  float* out_t = out + 2ull * (size_t)B * (size_t)K;
  float* out_v = out_t + B;

  double vloc = 0.0;
  float4 p4, r4;
  float pv[4], rv[4];
  #pragma unroll
  for (int t = 0; t < 4; ++t) {
    double x = zd[t] - tau;
    double p = x < 0.0 ? 0.0 : (x > ud[t] ? ud[t] : x);
    int reg = (p <= 0.0) ? 0 : ((p >= ud[t]) ? 2 : 1);
    double d = p - zd[t];
    vloc += d * d;
    pv[t] = (float)p;
    rv[t] = (float)reg;
  }
  p4.x = pv[0]; p4.y = pv[1]; p4.z = pv[2]; p4.w = pv[3];
  r4.x = rv[0]; r4.y = rv[1]; r4.z = rv[2]; r4.w = rv[3];
  ((float4*)(out_p + base))[tid] = p4;
  ((float4*)(out_r + base))[tid] = r4;

  #pragma unroll
  for (int off = 32; off; off >>= 1) vloc += __shfl_down(vloc, off);
  if (lane == 0) sA[wave] = vloc;
  __syncthreads();
  if (tid == 0) {
    double v = sA[0] + sA[1] + sA[2] + sA[3];
    out_t[row] = (float)tau;
    out_v[row] = (float)(0.5 * v);
  }
}

extern "C" void kernel_launch(void* const* d_in, const int* in_sizes, int n_in,
                              void* d_out, int out_size, void* d_ws, size_t ws_size,
                              hipStream_t stream) {
  const float* z = (const float*)d_in[0];
  const float* u = (const float*)d_in[1];
  float* out = (float*)d_out;
  const int K = 1024;
  const int B = in_sizes[0] / K;
  csparsemax_kernel<<<B, 256, 0, stream>>>(z, u, out, K, B);
}

// Round 2
// 49.878 us; speedup vs baseline: 2.0676x; 2.0676x over previous
//
#include <hip/hip_runtime.h>

// Constrained sparsemax, wave-per-row version.
// p = clip(z - tau, 0, u), tau s.t. f(tau) = sum clip(z - tau, 0, u) = 1.
// Phase 1: safeguarded Newton/bisection in f32 (cheap) to f32 fixed point.
// Phase 2: safeguarded Newton in f64 (global bracket) to exact f64 root.
// One wave (64 lanes) per row, K=1024 -> 16 elements/lane in registers.
// All reductions are __shfl_xor butterflies: every lane ends with the
// bit-identical sum -> uniform branches, no LDS, no __syncthreads.

__global__ __launch_bounds__(256)
void csparsemax_kernel(const float* __restrict__ z, const float* __restrict__ u,
                       float* __restrict__ out, int B) {
  constexpr int K = 1024;
  const int lane = threadIdx.x & 63;
  const int wave = threadIdx.x >> 6;
  const int row = blockIdx.x * 4 + wave;
  if (row >= B) return;
  const size_t base = (size_t)row * (size_t)K;

  // --- load 16 elems/lane as 4x float4, coalesced (lane-contiguous) ---
  float zf[16], uf[16];
  const float4* z4p = (const float4*)(z + base);
  const float4* u4p = (const float4*)(u + base);
  #pragma unroll
  for (int j = 0; j < 4; ++j) {
    float4 a = z4p[j * 64 + lane];
    float4 b = u4p[j * 64 + lane];
    zf[j*4+0] = a.x; zf[j*4+1] = a.y; zf[j*4+2] = a.z; zf[j*4+3] = a.w;
    uf[j*4+0] = b.x; uf[j*4+1] = b.y; uf[j*4+2] = b.z; uf[j*4+3] = b.w;
  }

  // --- global bracket: f(lo)=sum u>=1, f(hi)=0 ---
  float lo = 3.4e38f, hi = -3.4e38f;
  #pragma unroll
  for (int t = 0; t < 16; ++t) {
    lo = fminf(lo, zf[t] - uf[t]);
    hi = fmaxf(hi, zf[t]);
  }
  #pragma unroll
  for (int m = 32; m; m >>= 1) {
    lo = fminf(lo, __shfl_xor(lo, m));
    hi = fmaxf(hi, __shfl_xor(hi, m));
  }
  const float glo = lo, ghi = hi;

  // --- phase 1: f32 safeguarded Newton/bisection ---
  float tau = 0.5f * (lo + hi);
  for (int it = 0; it < 40; ++it) {
    float S0 = 0.f, S1 = 0.f, C0 = 0.f, C1 = 0.f;
    #pragma unroll
    for (int t = 0; t < 16; t += 2) {
      float xa = zf[t] - tau;
      float xb = zf[t+1] - tau;
      S0 += (xa >= uf[t])   ? uf[t]   : ((xa > 0.f) ? zf[t]   : 0.f);
      S1 += (xb >= uf[t+1]) ? uf[t+1] : ((xb > 0.f) ? zf[t+1] : 0.f);
      C0 += (xa > 0.f && xa < uf[t])   ? 1.f : 0.f;
      C1 += (xb > 0.f && xb < uf[t+1]) ? 1.f : 0.f;
    }
    float S = S0 + S1, C = C0 + C1;
    #pragma unroll
    for (int m = 32; m; m >>= 1) {
      S += __shfl_xor(S, m);
      C += __shfl_xor(C, m);
    }
    float f = S - C * tau;
    if (f > 1.f) lo = tau; else hi = tau;
    float next;
    if (C > 0.5f) {
      float cand = (S - 1.f) / C;
      if (cand == tau) break;               // f32 fixed point
      next = (cand > lo && cand < hi) ? cand : 0.5f * (lo + hi);
    } else {
      next = 0.5f * (lo + hi);
    }
    if (next == tau) break;                 // bracket exhausted in f32
    tau = next;
  }

  // --- phase 2: f64 safeguarded Newton, global bracket, start at f32 tau ---
  double dlo = glo, dhi = ghi;
  double taud = tau;
  for (int it = 0; it < 40; ++it) {
    double S = 0.0, C = 0.0;
    #pragma unroll
    for (int t = 0; t < 16; ++t) {
      double x = (double)zf[t] - taud;
      if (x >= (double)uf[t])      S += (double)uf[t];
      else if (x > 0.0)          { S += (double)zf[t]; C += 1.0; }
    }
    #pragma unroll
    for (int m = 32; m; m >>= 1) {
      S += __shfl_xor(S, m);
      C += __shfl_xor(C, m);
    }
    double f = S - C * taud;
    if (f == 1.0 && C > 0.5) break;
    if (f > 1.0) dlo = taud; else dhi = taud;
    double next;
    if (C > 0.5) {
      double cand = (S - 1.0) / C;
      if (cand == taud) break;              // exact f64 root
      next = (cand > dlo && cand < dhi) ? cand : 0.5 * (dlo + dhi);
    } else {
      next = 0.5 * (dlo + dhi);
    }
    if (next == taud) break;
    taud = next;
  }

  // --- epilogue: p, regions(as f32), tau, val ---
  float* out_p = out;
  float* out_r = out + (size_t)B * (size_t)K;
  float* out_t = out + 2ull * (size_t)B * (size_t)K;
  float* out_v = out_t + B;

  double vloc = 0.0;
  #pragma unroll
  for (int j = 0; j < 4; ++j) {
    float4 p4, r4;
    float pv[4], rv[4];
    #pragma unroll
    for (int q = 0; q < 4; ++q) {
      int t = j * 4 + q;
      double x = (double)zf[t] - taud;
      double ud = (double)uf[t];
      double p = x < 0.0 ? 0.0 : (x > ud ? ud : x);
      int reg = (p <= 0.0) ? 0 : ((p >= ud) ? 2 : 1);
      double d = p - (double)zf[t];
      vloc += d * d;
      pv[q] = (float)p;
      rv[q] = (float)reg;
    }
    p4.x = pv[0]; p4.y = pv[1]; p4.z = pv[2]; p4.w = pv[3];
    r4.x = rv[0]; r4.y = rv[1]; r4.z = rv[2]; r4.w = rv[3];
    ((float4*)(out_p + base))[j * 64 + lane] = p4;
    ((float4*)(out_r + base))[j * 64 + lane] = r4;
  }

  #pragma unroll
  for (int m = 32; m; m >>= 1) vloc += __shfl_xor(vloc, m);
  if (lane == 0) {
    out_t[row] = (float)taud;
    out_v[row] = (float)(0.5 * vloc);
  }
}

extern "C" void kernel_launch(void* const* d_in, const int* in_sizes, int n_in,
                              void* d_out, int out_size, void* d_ws, size_t ws_size,
                              hipStream_t stream) {
  const float* z = (const float*)d_in[0];
  const float* u = (const float*)d_in[1];
  float* out = (float*)d_out;
  const int K = 1024;
  const int B = in_sizes[0] / K;
  const int blocks = (B + 3) / 4;
  csparsemax_kernel<<<blocks, 256, 0, stream>>>(z, u, out, B);
}